// Round 7
// baseline (248.536 us; speedup 1.0000x reference)
//
#include <hip/hip_runtime.h>

// NODEModel MFMA fp16, R15: 32x32x16 MFMA shape (R9 structure, new fragments).
// R13/R14 established: issue-side work removal off the critical path is free
// but useless; the wall is the serialized {A-read -> MFMA -> tanh -> H LDS
// round trip} chain. R15 shrinks the MFMA phase: 32x32x16 is ~15% more
// FLOP/cy than 16x16x32 (2382 vs 2075 TF ubench) and halves instruction
// count; K=16 granularity lets the input layer (7 real features) run 1
// K-step instead of 2 (R9 multiplied 25 zero rows). Per chain-wave:
// 416 MFMA @19.4cy -> 200 @32.3cy (-20% matrix time, -52% issue slots).
// Same: 80KB LDS, 2 blocks/CU, barriers/staging/ring, 64 samples/wave,
// acc = 128 AGPR (4mt x 2nt x f32x16), tanh2_pk, scalar output dot.
// New layouts: A/B m=lane&31, k=8*(lane>>5)+j (2 groups of 32 lanes);
// C/D col=lane&31, row=(reg&3)+8*(reg>>2)+4*(lane>>5) (m74/m101-verified).
// H image per sample unchanged (16 swizzled 16B cols) -> output path same.
// Guard removed (R14: null, +1 launch).

#define NTHREADS 256
#define MLP_STRIDE 53248   // fp16 elems per MLP: 4096 WinA + 3*16384 Wh = 13 slabs
#define WINA_ELEMS 4096
#define SLAB_F16 4096      // 8 KB slab
#define TANH_SCALE 2.8853900817779268f   // 2*log2(e)

typedef _Float16 f16;
typedef f16 f16x8 __attribute__((ext_vector_type(8)));
typedef __fp16 fp16x2 __attribute__((ext_vector_type(2)));
typedef float f32x4 __attribute__((ext_vector_type(4)));
typedef float f32x16 __attribute__((ext_vector_type(16)));

// ---------------- prep: fp32 weights -> fp16 fragment-linear (pre-scaled) ----
// Slab layout (8KB): [mt(4)][kh(2)][lane(64)][j(8)] f16;
//   m = 32*mt + (lane&31), k = base + 16*kh + 8*(lane>>5) + j.
__global__ __launch_bounds__(NTHREADS)
void prep_kernel(const float* __restrict__ dp_Win, const float* __restrict__ dp_bin,
                 const float* __restrict__ dp_Wh,  const float* __restrict__ dp_bh,
                 const float* __restrict__ ic_Win, const float* __restrict__ ic_bin,
                 const float* __restrict__ ic_Wh,  const float* __restrict__ ic_bh,
                 f16* __restrict__ wsw)
{
    int e = blockIdx.x * NTHREADS + threadIdx.x;
    if (e >= 2 * MLP_STRIDE + 768) return;
    if (e >= 2 * MLP_STRIDE) {          // scaled hidden biases, fp32
        int idx = e - 2 * MLP_STRIDE;   // [mlp(2)][l(3)][m(128)]
        int mlp = idx / 384, rem = idx % 384;
        const float* bh = mlp ? ic_bh : dp_bh;
        float* bsc = (float*)(wsw + 2 * MLP_STRIDE);
        bsc[idx] = bh[rem] * TANH_SCALE;
        return;
    }
    int mlp = (e >= MLP_STRIDE) ? 1 : 0;   // 0 = dp, 1 = ic
    int r = e - mlp * MLP_STRIDE;
    const float* Win = mlp ? ic_Win : dp_Win;
    const float* bin = mlp ? ic_bin : dp_bin;
    const float* Wh  = mlp ? ic_Wh  : dp_Wh;
    int din = mlp ? 5 : 6;
    float val;
    if (r < WINA_ELEMS) {
        int mt = r >> 10, kh = (r >> 9) & 1, lane = (r >> 3) & 63, j = r & 7;
        int m = mt * 32 + (lane & 31);
        int k = kh * 16 + ((lane >> 5) << 3) + j;           // 0..31
        val = (k < din) ? Win[k * 128 + m] : ((k == din) ? bin[m] : 0.0f);
    } else {
        int r2 = r - WINA_ELEMS;
        int l = r2 >> 14, r3 = r2 & 16383;
        int ks = r3 >> 12, mt = (r3 >> 10) & 3, kh = (r3 >> 9) & 1;
        int lane = (r3 >> 3) & 63, j = r3 & 7;
        int m = mt * 32 + (lane & 31);
        int k = ks * 32 + kh * 16 + ((lane >> 5) << 3) + j; // 0..127
        val = Wh[(l * 128 + k) * 128 + m];
    }
    wsw[e] = (f16)(val * TANH_SCALE);
}

// ---------------- main ----------------
__device__ __forceinline__ unsigned int tanh2_pk(float x0, float x1) {
    // inputs pre-scaled by 2*log2e: tanh = 1 - 2/(exp2(x)+1).
    // Batched reciprocal: one rcp serves both values of the pair.
    float a0 = __builtin_amdgcn_exp2f(x0) + 1.0f;
    float a1 = __builtin_amdgcn_exp2f(x1) + 1.0f;
    float n2 = -2.0f * __builtin_amdgcn_rcpf(a0 * a1);
    union { fp16x2 h; unsigned int u; } c;
    c.h = __builtin_amdgcn_cvt_pkrtz(fmaf(n2, a1, 1.0f), fmaf(n2, a0, 1.0f));
    return c.u;
}

__device__ __forceinline__ int h_addr(int n, int kb) {
    return n * 256 + ((((kb >> 4) ^ (n & 7)) << 4) | (kb & 15));
}

__device__ __forceinline__ f32x16 mfma32(f16x8 a, f16x8 b, f32x16 c) {
    return __builtin_amdgcn_mfma_f32_32x32x16_f16(a, b, c, 0, 0, 0);
}

__device__ __forceinline__ void stage16(const void* g, void* l) {
    __builtin_amdgcn_global_load_lds((const __attribute__((address_space(1))) void*)g,
                                     (__attribute__((address_space(3))) void*)l, 16, 0, 0);
}

#define WAITCNT_VM0_LGKM0 0x0070   // vmcnt=0, expcnt=7 (dc), lgkmcnt=0

__global__ __launch_bounds__(NTHREADS, 2)
void node_main(const float* __restrict__ tx, const f16* __restrict__ wsw,
               const float* __restrict__ dp_Wout, const float* __restrict__ dp_bout,
               const float* __restrict__ ic_Wout, const float* __restrict__ ic_bout,
               float* __restrict__ out)
{
    __shared__ __align__(16) unsigned char lds_h[65536];     // 4 waves x 64 samples x 256 B
    __shared__ __align__(16) unsigned char lds_w[2][8192];   // ring

    const int tid  = threadIdx.x;
    const int lane = tid & 63;
    const int wv   = tid >> 6;
    const int l31  = lane & 31;
    const int hf   = lane >> 5;          // k-half group within fragment
    const int d7   = lane & 7;
    const int p0   = blockIdx.x * 256;

    // H row bases per ntile (n = wv*64 + nt*32 + l31; n&7 == d7 for both)
    int rrow[2];
    rrow[0] = (wv * 64 + l31) * 256;
    rrow[1] = rrow[0] + 32 * 256;

    const float* bsc = (const float*)(wsw + 2 * MLP_STRIDE);
    const float4* tx4 = (const float4*)tx;

    // features for the 2 ntile sample groups (meaningful in lanes 0..31)
    float rA[2], xA[2], yA[2], zA[2], iA[2], aA2[2];
    #pragma unroll
    for (int nt2 = 0; nt2 < 2; ++nt2) {
        float4 tv = tx4[p0 + wv * 64 + nt2 * 32 + l31];
        float xx = tv.y, yy = tv.z, zz = tv.w;
        float rr = sqrtf(fmaf(xx, xx, fmaf(yy, yy, zz * zz)));
        float irs = 1.0f / fmaxf(rr, 1e-8f);
        rA[nt2] = rr; xA[nt2] = xx * irs; yA[nt2] = yy * irs; zA[nt2] = zz * irs;
        iA[nt2] = 1.0f / (1.0f + rr);
        aA2[nt2] = 0.5f * tv.x;
    }
    // own sample (output layer): 1 sample per lane
    const int sown = wv * 64 + lane;
    float ao, io;
    {
        float4 tv = tx4[p0 + sown];
        float xx = tv.y, yy = tv.z, zz = tv.w;
        float rr = sqrtf(fmaf(xx, xx, fmaf(yy, yy, zz * zz)));
        io = 1.0f / (1.0f + rr);
        ao = 0.5f * tv.x;
    }

    const f32x16 z16 = {0.f,0.f,0.f,0.f, 0.f,0.f,0.f,0.f, 0.f,0.f,0.f,0.f, 0.f,0.f,0.f,0.f};
    float icv = 0.0f, dsum = 0.0f;
    int p = 0;

    // prologue: stage slab 0 of chain 0 (ic WinA) into slot 0
    {
        const char* g = (const char*)(wsw + MLP_STRIDE);
        stage16(g + tid * 16, &lds_w[0][0] + tid * 16);
        stage16(g + 4096 + tid * 16, &lds_w[0][0] + 4096 + tid * 16);
    }

    for (int c = 0; c < 4; ++c) {
        const f16* wb       = wsw + (c == 0 ? MLP_STRIDE : 0);
        const float* bb     = bsc + (c == 0 ? 384 : 0);
        const float* Wout   = (c == 0) ? ic_Wout : dp_Wout;
        const float* bout   = (c == 0) ? ic_bout : dp_bout;
        const float tn = (c == 1) ? 0.22540333075851662f
                       : ((c == 2) ? 1.0f : 1.7745966692414834f);   // node+1

        // ---- B frags for the input layer (lanes 0..31 hold real data, k=j) --
        f16x8 bfr[2];
        #pragma unroll
        for (int nt2 = 0; nt2 < 2; ++nt2) {
            f16x8 b = {};
            if (lane < 32) {
                if (c == 0) {
                    b[0] = (f16)rA[nt2]; b[1] = (f16)xA[nt2]; b[2] = (f16)yA[nt2];
                    b[3] = (f16)zA[nt2]; b[4] = (f16)iA[nt2]; b[5] = (f16)1.0f;
                } else {
                    b[0] = (f16)(aA2[nt2] * tn); b[1] = (f16)rA[nt2]; b[2] = (f16)xA[nt2];
                    b[3] = (f16)yA[nt2]; b[4] = (f16)zA[nt2]; b[5] = (f16)iA[nt2];
                    b[6] = (f16)1.0f;
                }
            }
            bfr[nt2] = b;
        }

        f32x16 acc[4][2];

        #pragma unroll 1
        for (int sw = 0; sw < 13; ++sw) {
            // ---- pipelined sync point ----
            __asm__ __volatile__("" ::: "memory");
            __builtin_amdgcn_s_waitcnt(WAITCNT_VM0_LGKM0);
            __builtin_amdgcn_s_barrier();
            __asm__ __volatile__("" ::: "memory");

            // ---- issue next slab's stage into the other slot ----
            if (!(c == 3 && sw == 12)) {
                const char* g = (sw < 12) ? (const char*)(wb + (sw + 1) * SLAB_F16)
                                          : (const char*)wsw;   // next chain = dp base
                unsigned char* dst = &lds_w[p ^ 1][0];
                stage16(g + tid * 16, dst + tid * 16);
                stage16(g + 4096 + tid * 16, dst + 4096 + tid * 16);
            }
            __asm__ __volatile__("" ::: "memory");

            const unsigned char* A = &lds_w[p][0];

            if (sw == 0) {
                // ---- input layer: K=16 only (features 0..6; k>=8 half is 0) --
                #pragma unroll
                for (int mt = 0; mt < 4; ++mt) {
                    f16x8 a0 = *(const f16x8*)(A + (((mt * 2 + 0) * 64 + lane) << 4));
                    acc[mt][0] = mfma32(a0, bfr[0], z16);
                    acc[mt][1] = mfma32(a0, bfr[1], z16);
                }
                #pragma unroll
                for (int mt = 0; mt < 4; ++mt) {
                    #pragma unroll
                    for (int nt2 = 0; nt2 < 2; ++nt2) {
                        f32x16 v = acc[mt][nt2];
                        #pragma unroll
                        for (int g2 = 0; g2 < 4; ++g2) {
                            uint2 o;
                            o.x = tanh2_pk(v[4 * g2 + 0], v[4 * g2 + 1]);
                            o.y = tanh2_pk(v[4 * g2 + 2], v[4 * g2 + 3]);
                            *(uint2*)(lds_h + rrow[nt2] + ((((4 * mt + g2) ^ d7)) << 4)
                                      + (hf << 3)) = o;
                        }
                    }
                }
            } else {
                // ---- hidden layer slab: l = (sw-1)/4, ks2 = (sw-1)%4 ----
                int l   = (sw - 1) >> 2;
                int ks2 = (sw - 1) & 3;
                f16x8 hb[2][2];
                #pragma unroll
                for (int nt2 = 0; nt2 < 2; ++nt2)
                    #pragma unroll
                    for (int kh = 0; kh < 2; ++kh)
                        hb[nt2][kh] = *(const f16x8*)(lds_h + rrow[nt2]
                                        + (((4 * ks2 + 2 * kh + hf) ^ d7) << 4));
                if (ks2 == 0) {
                    const float* bl = bb + l * 128;
                    #pragma unroll
                    for (int mt = 0; mt < 4; ++mt) {
                        f32x16 c16;
                        #pragma unroll
                        for (int g2 = 0; g2 < 4; ++g2) {
                            f32x4 t = *(const f32x4*)(bl + 32 * mt + 8 * g2 + 4 * hf);
                            c16[4 * g2 + 0] = t[0]; c16[4 * g2 + 1] = t[1];
                            c16[4 * g2 + 2] = t[2]; c16[4 * g2 + 3] = t[3];
                        }
                        f16x8 a0 = *(const f16x8*)(A + (((mt * 2 + 0) * 64 + lane) << 4));
                        f16x8 a1 = *(const f16x8*)(A + (((mt * 2 + 1) * 64 + lane) << 4));
                        acc[mt][0] = mfma32(a1, hb[0][1], mfma32(a0, hb[0][0], c16));
                        acc[mt][1] = mfma32(a1, hb[1][1], mfma32(a0, hb[1][0], c16));
                    }
                } else {
                    #pragma unroll
                    for (int mt = 0; mt < 4; ++mt) {
                        f16x8 a0 = *(const f16x8*)(A + (((mt * 2 + 0) * 64 + lane) << 4));
                        f16x8 a1 = *(const f16x8*)(A + (((mt * 2 + 1) * 64 + lane) << 4));
                        acc[mt][0] = mfma32(a1, hb[0][1], mfma32(a0, hb[0][0], acc[mt][0]));
                        acc[mt][1] = mfma32(a1, hb[1][1], mfma32(a0, hb[1][0], acc[mt][1]));
                    }
                }
                if (ks2 == 3) {
                    #pragma unroll
                    for (int mt = 0; mt < 4; ++mt) {
                        #pragma unroll
                        for (int nt2 = 0; nt2 < 2; ++nt2) {
                            f32x16 v = acc[mt][nt2];
                            #pragma unroll
                            for (int g2 = 0; g2 < 4; ++g2) {
                                uint2 o;
                                o.x = tanh2_pk(v[4 * g2 + 0], v[4 * g2 + 1]);
                                o.y = tanh2_pk(v[4 * g2 + 2], v[4 * g2 + 3]);
                                *(uint2*)(lds_h + rrow[nt2] + ((((4 * mt + g2) ^ d7)) << 4)
                                          + (hf << 3)) = o;
                            }
                        }
                    }
                }
            }
            p ^= 1;
        }

        // ---- output layer: 1 sample per lane, 128-elem dot from own H ----
        {
            float sum = 0.0f;
            #pragma unroll
            for (int u = 0; u < 16; ++u) {
                f16x8 hv = *(const f16x8*)(lds_h + h_addr(sown, u * 16));
                f32x4 w0 = *(const f32x4*)(Wout + u * 8);
                f32x4 w1 = *(const f32x4*)(Wout + u * 8 + 4);
                sum = fmaf((float)hv[0], w0[0], sum);
                sum = fmaf((float)hv[1], w0[1], sum);
                sum = fmaf((float)hv[2], w0[2], sum);
                sum = fmaf((float)hv[3], w0[3], sum);
                sum = fmaf((float)hv[4], w1[0], sum);
                sum = fmaf((float)hv[5], w1[1], sum);
                sum = fmaf((float)hv[6], w1[2], sum);
                sum = fmaf((float)hv[7], w1[3], sum);
            }
            float val = sum + bout[0];
            if (c == 0) icv = val;
            else        dsum = fmaf((c == 2) ? (8.0f / 9.0f) : (5.0f / 9.0f), val, dsum);
        }
    }

    out[p0 + sown] = (icv + ao * dsum) * io;
}

extern "C" void kernel_launch(void* const* d_in, const int* in_sizes, int n_in,
                              void* d_out, int out_size, void* d_ws, size_t ws_size,
                              hipStream_t stream) {
    const float* tx      = (const float*)d_in[0];
    const float* dp_Win  = (const float*)d_in[1];
    const float* dp_bin  = (const float*)d_in[2];
    const float* dp_Wh   = (const float*)d_in[3];
    const float* dp_bh   = (const float*)d_in[4];
    const float* dp_Wout = (const float*)d_in[5];
    const float* dp_bout = (const float*)d_in[6];
    const float* ic_Win  = (const float*)d_in[7];
    const float* ic_bin  = (const float*)d_in[8];
    const float* ic_Wh   = (const float*)d_in[9];
    const float* ic_bh   = (const float*)d_in[10];
    const float* ic_Wout = (const float*)d_in[11];
    const float* ic_bout = (const float*)d_in[12];
    float* out = (float*)d_out;
    f16* wsw = (f16*)d_ws;

    int n = in_sizes[0] / 4;

    prep_kernel<<<dim3((2 * MLP_STRIDE + 768 + NTHREADS - 1) / NTHREADS), dim3(NTHREADS), 0, stream>>>(
        dp_Win, dp_bin, dp_Wh, dp_bh, ic_Win, ic_bin, ic_Wh, ic_bh, wsw);

    node_main<<<dim3(n / 256), dim3(NTHREADS), 0, stream>>>(
        tx, wsw, dp_Wout, dp_bout, ic_Wout, ic_bout, out);
}

// Round 8
// 225.698 us; speedup vs baseline: 1.1012x; 1.1012x over previous
//
#include <hip/hip_runtime.h>

// NODEModel MFMA fp16, R16: in-register H via weight-side k-permutation.
// R13 (trans -25%) and R15 (MFMA insts -52%) both left dur at ~197us ->
// no issue pipe is critical; ~3K cy/slab of latency stall is. Constant
// SQ_LDS_BANK_CONFLICT=1.258e7 across ALL variants localizes to the
// output-layer h_addr reads (256B row stride -> bank=f(col), ~8-way).
// R16 deletes the H LDS entirely: prep permutes each hidden Wh slab's
// k-rows by tau(16t+8h+j)=16t+8*(j>>2)+4h+(j&3); then (from R15-verified
// C/D layout m=(r&3)+8*(r>>2)+4*(lane>>5)+32mt) the next layer's B-frag
// [ks2][kh] elem j = tanh(acc[ks2][8kh+j]) -- 8 consecutive OWN regs.
// No cross-lane, no ds_write/ds_read for H, no lgkm H-coupling. Output
// dot runs from acc regs in f32 (Wout gathered as f32x4 at 32mt+8q+4h,
// 2 distinct addrs/wave -> broadcast) + one shfl_xor(32) pair-reduce.
// LDS = 16KB ring only. sw loop fully unrolled (bfrag indices static,
// rule #20). Same: ring staging, vmcnt(0)+barrier per slab, 64 smp/wave,
// tanh2_pk for frag-build, launch_bounds(256,2).

#define NTHREADS 256
#define MLP_STRIDE 53248   // fp16 elems per MLP: 4096 WinA + 3*16384 Wh = 13 slabs
#define WINA_ELEMS 4096
#define SLAB_F16 4096      // 8 KB slab
#define TANH_SCALE 2.8853900817779268f   // 2*log2(e)

typedef _Float16 f16;
typedef f16 f16x8 __attribute__((ext_vector_type(8)));
typedef __fp16 fp16x2 __attribute__((ext_vector_type(2)));
typedef float f32x4 __attribute__((ext_vector_type(4)));
typedef float f32x16 __attribute__((ext_vector_type(16)));

// ---------------- prep: fp32 weights -> fp16 fragment-linear (pre-scaled) ----
// Slab layout (8KB): [mt(4)][kh(2)][lane(64)][j(8)] f16;
//   m = 32*mt + (lane&31), k_slot = base + 16*kh + 8*(lane>>5) + j.
// Hidden slabs: weight k-row = tau(k_slot) so next-layer B comes from acc regs.
__global__ __launch_bounds__(NTHREADS)
void prep_kernel(const float* __restrict__ dp_Win, const float* __restrict__ dp_bin,
                 const float* __restrict__ dp_Wh,  const float* __restrict__ dp_bh,
                 const float* __restrict__ ic_Win, const float* __restrict__ ic_bin,
                 const float* __restrict__ ic_Wh,  const float* __restrict__ ic_bh,
                 f16* __restrict__ wsw)
{
    int e = blockIdx.x * NTHREADS + threadIdx.x;
    if (e >= 2 * MLP_STRIDE + 768) return;
    if (e >= 2 * MLP_STRIDE) {          // scaled hidden biases, fp32
        int idx = e - 2 * MLP_STRIDE;   // [mlp(2)][l(3)][m(128)]
        int mlp = idx / 384, rem = idx % 384;
        const float* bh = mlp ? ic_bh : dp_bh;
        float* bsc = (float*)(wsw + 2 * MLP_STRIDE);
        bsc[idx] = bh[rem] * TANH_SCALE;
        return;
    }
    int mlp = (e >= MLP_STRIDE) ? 1 : 0;   // 0 = dp, 1 = ic
    int r = e - mlp * MLP_STRIDE;
    const float* Win = mlp ? ic_Win : dp_Win;
    const float* bin = mlp ? ic_bin : dp_bin;
    const float* Wh  = mlp ? ic_Wh  : dp_Wh;
    int din = mlp ? 5 : 6;
    float val;
    if (r < WINA_ELEMS) {
        int mt = r >> 10, kh = (r >> 9) & 1, lane = (r >> 3) & 63, j = r & 7;
        int m = mt * 32 + (lane & 31);
        int k = kh * 16 + ((lane >> 5) << 3) + j;           // feature index, natural
        val = (k < din) ? Win[k * 128 + m] : ((k == din) ? bin[m] : 0.0f);
    } else {
        int r2 = r - WINA_ELEMS;
        int l = r2 >> 14, r3 = r2 & 16383;
        int ks = r3 >> 12, mt = (r3 >> 10) & 3, kh = (r3 >> 9) & 1;
        int lane = (r3 >> 3) & 63, j = r3 & 7;
        int m = mt * 32 + (lane & 31);
        int k = ks * 32 + kh * 16 + ((lane >> 5) << 3) + j; // slot 0..127
        // tau: slot k=16t+8h'+j' holds prev-layer unit 16t+8*(j'>>2)+4h'+(j'&3)
        int kt = (k & ~15) | (((k & 7) >> 2) << 3) | (((k >> 3) & 1) << 2) | (k & 3);
        val = Wh[(l * 128 + kt) * 128 + m];
    }
    wsw[e] = (f16)(val * TANH_SCALE);
}

// ---------------- main ----------------
__device__ __forceinline__ float tanh_fast(float x) {
    // input pre-scaled by 2*log2e: tanh = 1 - 2/(exp2(x)+1)
    float e = __builtin_amdgcn_exp2f(x);
    float r = __builtin_amdgcn_rcpf(e + 1.0f);
    return fmaf(-2.0f, r, 1.0f);
}

__device__ __forceinline__ unsigned int tanh2_pk(float x0, float x1) {
    // batched reciprocal: one rcp serves both values of the pair
    float a0 = __builtin_amdgcn_exp2f(x0) + 1.0f;
    float a1 = __builtin_amdgcn_exp2f(x1) + 1.0f;
    float n2 = -2.0f * __builtin_amdgcn_rcpf(a0 * a1);
    union { fp16x2 h; unsigned int u; } c;
    c.h = __builtin_amdgcn_cvt_pkrtz(fmaf(n2, a1, 1.0f), fmaf(n2, a0, 1.0f));
    return c.u;
}

__device__ __forceinline__ f32x16 mfma32(f16x8 a, f16x8 b, f32x16 c) {
    return __builtin_amdgcn_mfma_f32_32x32x16_f16(a, b, c, 0, 0, 0);
}

__device__ __forceinline__ void stage16(const void* g, void* l) {
    __builtin_amdgcn_global_load_lds((const __attribute__((address_space(1))) void*)g,
                                     (__attribute__((address_space(3))) void*)l, 16, 0, 0);
}

#define WAITCNT_VM0_LGKM0 0x0070   // vmcnt=0, expcnt=7 (dc), lgkmcnt=0

__global__ __launch_bounds__(NTHREADS, 2)
void node_main(const float* __restrict__ tx, const f16* __restrict__ wsw,
               const float* __restrict__ dp_Wout, const float* __restrict__ dp_bout,
               const float* __restrict__ ic_Wout, const float* __restrict__ ic_bout,
               float* __restrict__ out)
{
    __shared__ __align__(16) unsigned char lds_w[2][8192];   // weight ring only

    const int tid  = threadIdx.x;
    const int lane = tid & 63;
    const int wv   = tid >> 6;
    const int l31  = lane & 31;
    const int hf   = lane >> 5;
    const int p0   = blockIdx.x * 256;

    const float* bsc = (const float*)(wsw + 2 * MLP_STRIDE);
    const float4* tx4 = (const float4*)tx;

    // features for the 2 ntile sample groups (meaningful in lanes 0..31)
    float rA[2], xA[2], yA[2], zA[2], iA[2], aA2[2];
    #pragma unroll
    for (int nt2 = 0; nt2 < 2; ++nt2) {
        float4 tv = tx4[p0 + wv * 64 + nt2 * 32 + l31];
        float xx = tv.y, yy = tv.z, zz = tv.w;
        float rr = sqrtf(fmaf(xx, xx, fmaf(yy, yy, zz * zz)));
        float irs = 1.0f / fmaxf(rr, 1e-8f);
        rA[nt2] = rr; xA[nt2] = xx * irs; yA[nt2] = yy * irs; zA[nt2] = zz * irs;
        iA[nt2] = 1.0f / (1.0f + rr);
        aA2[nt2] = 0.5f * tv.x;
    }
    // own sample (output write): lane <-> sample wv*64 + 32*hf + l31 == wv*64+lane
    const int sown = wv * 64 + lane;
    float ao, io;
    {
        float4 tv = tx4[p0 + sown];
        float xx = tv.y, yy = tv.z, zz = tv.w;
        float rr = sqrtf(fmaf(xx, xx, fmaf(yy, yy, zz * zz)));
        io = 1.0f / (1.0f + rr);
        ao = 0.5f * tv.x;
    }

    const f32x16 z16 = {0.f,0.f,0.f,0.f, 0.f,0.f,0.f,0.f, 0.f,0.f,0.f,0.f, 0.f,0.f,0.f,0.f};
    float icv = 0.0f, dsum = 0.0f;
    int p = 0;

    // prologue: stage slab 0 of chain 0 (ic WinA) into slot 0
    {
        const char* g = (const char*)(wsw + MLP_STRIDE);
        stage16(g + tid * 16, &lds_w[0][0] + tid * 16);
        stage16(g + 4096 + tid * 16, &lds_w[0][0] + 4096 + tid * 16);
    }

    #pragma unroll 1
    for (int c = 0; c < 4; ++c) {
        const f16* wb       = wsw + (c == 0 ? MLP_STRIDE : 0);
        const float* bb     = bsc + (c == 0 ? 384 : 0);
        const float* Wout   = (c == 0) ? ic_Wout : dp_Wout;
        const float* bout   = (c == 0) ? ic_bout : dp_bout;
        const float tn = (c == 1) ? 0.22540333075851662f
                       : ((c == 2) ? 1.0f : 1.7745966692414834f);   // node+1

        // ---- B frags for the input layer (lanes 0..31 hold real data, k=j) --
        f16x8 bfr[2];
        #pragma unroll
        for (int nt2 = 0; nt2 < 2; ++nt2) {
            f16x8 b = {};
            if (lane < 32) {
                if (c == 0) {
                    b[0] = (f16)rA[nt2]; b[1] = (f16)xA[nt2]; b[2] = (f16)yA[nt2];
                    b[3] = (f16)zA[nt2]; b[4] = (f16)iA[nt2]; b[5] = (f16)1.0f;
                } else {
                    b[0] = (f16)(aA2[nt2] * tn); b[1] = (f16)rA[nt2]; b[2] = (f16)xA[nt2];
                    b[3] = (f16)yA[nt2]; b[4] = (f16)zA[nt2]; b[5] = (f16)iA[nt2];
                    b[6] = (f16)1.0f;
                }
            }
            bfr[nt2] = b;
        }

        f32x16 acc[4][2];
        f16x8 bfrag[4][2][2];   // [ks2][kh][nt] next-layer B operands (in-reg H)

        #pragma unroll
        for (int sw = 0; sw < 13; ++sw) {
            // ---- pipelined sync point ----
            __asm__ __volatile__("" ::: "memory");
            __builtin_amdgcn_s_waitcnt(WAITCNT_VM0_LGKM0);
            __builtin_amdgcn_s_barrier();
            __asm__ __volatile__("" ::: "memory");

            // ---- issue next slab's stage into the other slot ----
            if (!(c == 3 && sw == 12)) {
                const char* g = (sw < 12) ? (const char*)(wb + (sw + 1) * SLAB_F16)
                                          : (const char*)wsw;   // next chain = dp base
                unsigned char* dst = &lds_w[p ^ 1][0];
                stage16(g + tid * 16, dst + tid * 16);
                stage16(g + 4096 + tid * 16, dst + 4096 + tid * 16);
            }
            __asm__ __volatile__("" ::: "memory");

            const unsigned char* A = &lds_w[p][0];

            if (sw == 0) {
                // ---- input layer: K=16 only (features 0..6; kh=1 half is 0) --
                #pragma unroll
                for (int mt = 0; mt < 4; ++mt) {
                    f16x8 a0 = *(const f16x8*)(A + (((mt * 2 + 0) * 64 + lane) << 4));
                    acc[mt][0] = mfma32(a0, bfr[0], z16);
                    acc[mt][1] = mfma32(a0, bfr[1], z16);
                }
                // frag-build: B[ks2=mt][kh] elem j = tanh(acc[mt][8kh+j])
                #pragma unroll
                for (int mt = 0; mt < 4; ++mt)
                    #pragma unroll
                    for (int nt = 0; nt < 2; ++nt)
                        #pragma unroll
                        for (int kh = 0; kh < 2; ++kh) {
                            union { f16x8 f; unsigned u[4]; } w;
                            #pragma unroll
                            for (int q = 0; q < 4; ++q)
                                w.u[q] = tanh2_pk(acc[mt][nt][8 * kh + 2 * q],
                                                  acc[mt][nt][8 * kh + 2 * q + 1]);
                            bfrag[mt][kh][nt] = w.f;
                        }
            } else {
                // ---- hidden layer slab: l = (sw-1)/4, ks2 = (sw-1)%4 ----
                const int l   = (sw - 1) >> 2;
                const int ks2 = (sw - 1) & 3;
                if (ks2 == 0) {
                    const float* bl = bb + l * 128;
                    #pragma unroll
                    for (int mt = 0; mt < 4; ++mt) {
                        f32x16 c16;
                        #pragma unroll
                        for (int g2 = 0; g2 < 4; ++g2) {
                            f32x4 t = *(const f32x4*)(bl + 32 * mt + 8 * g2 + 4 * hf);
                            c16[4 * g2 + 0] = t[0]; c16[4 * g2 + 1] = t[1];
                            c16[4 * g2 + 2] = t[2]; c16[4 * g2 + 3] = t[3];
                        }
                        f16x8 a0 = *(const f16x8*)(A + (((mt * 2 + 0) * 64 + lane) << 4));
                        f16x8 a1 = *(const f16x8*)(A + (((mt * 2 + 1) * 64 + lane) << 4));
                        acc[mt][0] = mfma32(a1, bfrag[0][1][0], mfma32(a0, bfrag[0][0][0], c16));
                        acc[mt][1] = mfma32(a1, bfrag[0][1][1], mfma32(a0, bfrag[0][0][1], c16));
                    }
                } else {
                    #pragma unroll
                    for (int mt = 0; mt < 4; ++mt) {
                        f16x8 a0 = *(const f16x8*)(A + (((mt * 2 + 0) * 64 + lane) << 4));
                        f16x8 a1 = *(const f16x8*)(A + (((mt * 2 + 1) * 64 + lane) << 4));
                        acc[mt][0] = mfma32(a1, bfrag[ks2][1][0], mfma32(a0, bfrag[ks2][0][0], acc[mt][0]));
                        acc[mt][1] = mfma32(a1, bfrag[ks2][1][1], mfma32(a0, bfrag[ks2][0][1], acc[mt][1]));
                    }
                }
                if (ks2 == 3 && l < 2) {
                    // frag-build for next layer (overwrites consumed bfrag)
                    #pragma unroll
                    for (int mt = 0; mt < 4; ++mt)
                        #pragma unroll
                        for (int nt = 0; nt < 2; ++nt)
                            #pragma unroll
                            for (int kh = 0; kh < 2; ++kh) {
                                union { f16x8 f; unsigned u[4]; } w;
                                #pragma unroll
                                for (int q = 0; q < 4; ++q)
                                    w.u[q] = tanh2_pk(acc[mt][nt][8 * kh + 2 * q],
                                                      acc[mt][nt][8 * kh + 2 * q + 1]);
                                bfrag[mt][kh][nt] = w.f;
                            }
                }
            }
            p ^= 1;
        }

        // ---- output layer: f32 dot from acc regs (rows m = 32mt+8q+4hf+i) ----
        {
            float part0 = 0.0f, part1 = 0.0f;
            #pragma unroll
            for (int mt = 0; mt < 4; ++mt) {
                #pragma unroll
                for (int q = 0; q < 4; ++q) {
                    f32x4 w4 = *(const f32x4*)(Wout + 32 * mt + 8 * q + 4 * hf);
                    #pragma unroll
                    for (int i = 0; i < 4; ++i) {
                        part0 = fmaf(tanh_fast(acc[mt][0][4 * q + i]), w4[i], part0);
                        part1 = fmaf(tanh_fast(acc[mt][1][4 * q + i]), w4[i], part1);
                    }
                }
            }
            float s0 = part0 + __shfl_xor(part0, 32);
            float s1 = part1 + __shfl_xor(part1, 32);
            float val = (hf ? s1 : s0) + bout[0];
            if (c == 0) icv = val;
            else        dsum = fmaf((c == 2) ? (8.0f / 9.0f) : (5.0f / 9.0f), val, dsum);
        }
    }

    out[p0 + sown] = (icv + ao * dsum) * io;
}

extern "C" void kernel_launch(void* const* d_in, const int* in_sizes, int n_in,
                              void* d_out, int out_size, void* d_ws, size_t ws_size,
                              hipStream_t stream) {
    const float* tx      = (const float*)d_in[0];
    const float* dp_Win  = (const float*)d_in[1];
    const float* dp_bin  = (const float*)d_in[2];
    const float* dp_Wh   = (const float*)d_in[3];
    const float* dp_bh   = (const float*)d_in[4];
    const float* dp_Wout = (const float*)d_in[5];
    const float* dp_bout = (const float*)d_in[6];
    const float* ic_Win  = (const float*)d_in[7];
    const float* ic_bin  = (const float*)d_in[8];
    const float* ic_Wh   = (const float*)d_in[9];
    const float* ic_bh   = (const float*)d_in[10];
    const float* ic_Wout = (const float*)d_in[11];
    const float* ic_bout = (const float*)d_in[12];
    float* out = (float*)d_out;
    f16* wsw = (f16*)d_ws;

    int n = in_sizes[0] / 4;

    prep_kernel<<<dim3((2 * MLP_STRIDE + 768 + NTHREADS - 1) / NTHREADS), dim3(NTHREADS), 0, stream>>>(
        dp_Win, dp_bin, dp_Wh, dp_bh, ic_Win, ic_bin, ic_Wh, ic_bh, wsw);

    node_main<<<dim3(n / 256), dim3(NTHREADS), 0, stream>>>(
        tx, wsw, dp_Wout, dp_bout, ic_Wout, ic_bout, out);
}

// Round 9
// 224.896 us; speedup vs baseline: 1.1051x; 1.0036x over previous
//
#include <hip/hip_runtime.h>

// NODEModel MFMA fp16, R17: counted-vmcnt paired staging (T3/T4) on R16.
// R16 post-mortem: H-LDS removal won -11% and zeroed bank conflicts exactly
// as predicted. Remaining per-slab interval 4053 cy = 1034 matrix + ~1390
// VALU/trans + ~1630 idle -> the 52 vmcnt(0)-drain barriers are the last
// structural overhead (all compute is wave-local now; only the weight ring
// couples waves).
// R17: 13 slabs -> 7 sync groups {0},{1,2},...,{11,12}; 3-slot x 16KB ring;
// stage 2 groups ahead; wait vmcnt(4) (S0-S5), vmcnt(2) at S6 (next-chain G0
// in flight; in-order vmcnt retirement makes counts exact), vmcnt(0) only at
// the very last sync. 28 syncs/block, prefetch never drained mid-loop.
// To keep the counted window exact, ALL other vmem is eliminated from the
// loop: bias (768 f32) + Wout (2x128) + bout live in LDS (one-time copy at
// entry; reads are lgkm ds_reads, broadcast -> conflict-free). tx loads
// retire before the prologue; 'out' store is after the last sync.
// Unchanged from R16: tau weight permutation (in-reg H), 32x32x16 MFMA,
// tanh2_pk, 64 samples/wave, launch_bounds(256,2).

#define NTHREADS 256
#define MLP_STRIDE 53248   // fp16 elems per MLP: 4096 WinA + 3*16384 Wh = 13 slabs
#define WINA_ELEMS 4096
#define SLAB_F16 4096      // 8 KB slab
#define TANH_SCALE 2.8853900817779268f   // 2*log2(e)

typedef _Float16 f16;
typedef f16 f16x8 __attribute__((ext_vector_type(8)));
typedef __fp16 fp16x2 __attribute__((ext_vector_type(2)));
typedef float f32x4 __attribute__((ext_vector_type(4)));
typedef float f32x16 __attribute__((ext_vector_type(16)));

// ---------------- prep: fp32 weights -> fp16 fragment-linear (pre-scaled) ----
// Slab layout (8KB): [mt(4)][kh(2)][lane(64)][j(8)] f16;
//   m = 32*mt + (lane&31), k_slot = base + 16*kh + 8*(lane>>5) + j.
// Hidden slabs: weight k-row = tau(k_slot) so next-layer B comes from acc regs.
__global__ __launch_bounds__(NTHREADS)
void prep_kernel(const float* __restrict__ dp_Win, const float* __restrict__ dp_bin,
                 const float* __restrict__ dp_Wh,  const float* __restrict__ dp_bh,
                 const float* __restrict__ ic_Win, const float* __restrict__ ic_bin,
                 const float* __restrict__ ic_Wh,  const float* __restrict__ ic_bh,
                 f16* __restrict__ wsw)
{
    int e = blockIdx.x * NTHREADS + threadIdx.x;
    if (e >= 2 * MLP_STRIDE + 768) return;
    if (e >= 2 * MLP_STRIDE) {          // scaled hidden biases, fp32
        int idx = e - 2 * MLP_STRIDE;   // [mlp(2)][l(3)][m(128)]
        int mlp = idx / 384, rem = idx % 384;
        const float* bh = mlp ? ic_bh : dp_bh;
        float* bsc = (float*)(wsw + 2 * MLP_STRIDE);
        bsc[idx] = bh[rem] * TANH_SCALE;
        return;
    }
    int mlp = (e >= MLP_STRIDE) ? 1 : 0;   // 0 = dp, 1 = ic
    int r = e - mlp * MLP_STRIDE;
    const float* Win = mlp ? ic_Win : dp_Win;
    const float* bin = mlp ? ic_bin : dp_bin;
    const float* Wh  = mlp ? ic_Wh  : dp_Wh;
    int din = mlp ? 5 : 6;
    float val;
    if (r < WINA_ELEMS) {
        int mt = r >> 10, kh = (r >> 9) & 1, lane = (r >> 3) & 63, j = r & 7;
        int m = mt * 32 + (lane & 31);
        int k = kh * 16 + ((lane >> 5) << 3) + j;           // feature index, natural
        val = (k < din) ? Win[k * 128 + m] : ((k == din) ? bin[m] : 0.0f);
    } else {
        int r2 = r - WINA_ELEMS;
        int l = r2 >> 14, r3 = r2 & 16383;
        int ks = r3 >> 12, mt = (r3 >> 10) & 3, kh = (r3 >> 9) & 1;
        int lane = (r3 >> 3) & 63, j = r3 & 7;
        int m = mt * 32 + (lane & 31);
        int k = ks * 32 + kh * 16 + ((lane >> 5) << 3) + j; // slot 0..127
        // tau: slot k=16t+8h'+j' holds prev-layer unit 16t+8*(j'>>2)+4h'+(j'&3)
        int kt = (k & ~15) | (((k & 7) >> 2) << 3) | (((k >> 3) & 1) << 2) | (k & 3);
        val = Wh[(l * 128 + kt) * 128 + m];
    }
    wsw[e] = (f16)(val * TANH_SCALE);
}

// ---------------- main helpers ----------------
__device__ __forceinline__ float tanh_fast(float x) {
    float e = __builtin_amdgcn_exp2f(x);
    float r = __builtin_amdgcn_rcpf(e + 1.0f);
    return fmaf(-2.0f, r, 1.0f);
}

__device__ __forceinline__ unsigned int tanh2_pk(float x0, float x1) {
    float a0 = __builtin_amdgcn_exp2f(x0) + 1.0f;
    float a1 = __builtin_amdgcn_exp2f(x1) + 1.0f;
    float n2 = -2.0f * __builtin_amdgcn_rcpf(a0 * a1);
    union { fp16x2 h; unsigned int u; } c;
    c.h = __builtin_amdgcn_cvt_pkrtz(fmaf(n2, a1, 1.0f), fmaf(n2, a0, 1.0f));
    return c.u;
}

__device__ __forceinline__ f32x16 mfma32(f16x8 a, f16x8 b, f32x16 c) {
    return __builtin_amdgcn_mfma_f32_32x32x16_f16(a, b, c, 0, 0, 0);
}

__device__ __forceinline__ void stage16(const void* g, void* l) {
    __builtin_amdgcn_global_load_lds((const __attribute__((address_space(1))) void*)g,
                                     (__attribute__((address_space(3))) void*)l, 16, 0, 0);
}

__device__ __forceinline__ void stage_slab(const f16* g, unsigned char* dst, int tid) {
    stage16((const char*)g + tid * 16, dst + tid * 16);
    stage16((const char*)g + 4096 + tid * 16, dst + 4096 + tid * 16);
}

__device__ __forceinline__ f16x8 lda(const unsigned char* A, int idx, int lane) {
    return *(const f16x8*)(A + ((idx * 64 + lane) << 4));
}

// sync: counted vmcnt + lgkmcnt(0) + barrier
#define SYNC(ENC) do { \
    __asm__ __volatile__("" ::: "memory"); \
    __builtin_amdgcn_s_waitcnt(ENC); \
    __builtin_amdgcn_s_barrier(); \
    __asm__ __volatile__("" ::: "memory"); \
} while (0)
#define VM4 0x0074   // vmcnt=4, expcnt=7, lgkmcnt=0
#define VM2 0x0072
#define VM0 0x0070

__device__ __forceinline__ void frag_build(const f32x16 (&acc)[4][2], f16x8 (&bf)[4][2][2]) {
    #pragma unroll
    for (int mt = 0; mt < 4; ++mt)
        #pragma unroll
        for (int nt = 0; nt < 2; ++nt)
            #pragma unroll
            for (int kh = 0; kh < 2; ++kh) {
                union { f16x8 f; unsigned u[4]; } w;
                #pragma unroll
                for (int q = 0; q < 4; ++q)
                    w.u[q] = tanh2_pk(acc[mt][nt][8 * kh + 2 * q],
                                      acc[mt][nt][8 * kh + 2 * q + 1]);
                bf[mt][kh][nt] = w.f;
            }
}

__device__ __forceinline__ void input_slab(const unsigned char* A, int lane,
                                           const f16x8 (&bfr)[2], f32x16 (&acc)[4][2]) {
    const f32x16 z16 = {0.f,0.f,0.f,0.f, 0.f,0.f,0.f,0.f, 0.f,0.f,0.f,0.f, 0.f,0.f,0.f,0.f};
    #pragma unroll
    for (int mt = 0; mt < 4; ++mt) {
        f16x8 a0 = lda(A, mt * 2, lane);
        acc[mt][0] = mfma32(a0, bfr[0], z16);
        acc[mt][1] = mfma32(a0, bfr[1], z16);
    }
}

// pair of slabs: first = ks2 0 (bias C-init from LDS), second = ks2 1
__device__ __forceinline__ void hidden2_bias(const unsigned char* A, int lane, int hf,
                                             const float* lb_l,
                                             f32x16 (&acc)[4][2], const f16x8 (&bf)[4][2][2]) {
    #pragma unroll
    for (int mt = 0; mt < 4; ++mt) {
        f32x16 c16;
        #pragma unroll
        for (int g2 = 0; g2 < 4; ++g2) {
            f32x4 t = *(const f32x4*)(lb_l + 32 * mt + 8 * g2 + 4 * hf);
            c16[4 * g2 + 0] = t[0]; c16[4 * g2 + 1] = t[1];
            c16[4 * g2 + 2] = t[2]; c16[4 * g2 + 3] = t[3];
        }
        f16x8 a0 = lda(A, mt * 2, lane), a1 = lda(A, mt * 2 + 1, lane);
        acc[mt][0] = mfma32(a1, bf[0][1][0], mfma32(a0, bf[0][0][0], c16));
        acc[mt][1] = mfma32(a1, bf[0][1][1], mfma32(a0, bf[0][0][1], c16));
    }
    const unsigned char* B = A + 8192;
    #pragma unroll
    for (int mt = 0; mt < 4; ++mt) {
        f16x8 a0 = lda(B, mt * 2, lane), a1 = lda(B, mt * 2 + 1, lane);
        acc[mt][0] = mfma32(a1, bf[1][1][0], mfma32(a0, bf[1][0][0], acc[mt][0]));
        acc[mt][1] = mfma32(a1, bf[1][1][1], mfma32(a0, bf[1][0][1], acc[mt][1]));
    }
}

// pair of slabs: ks2 2 then ks2 3 (accumulate)
__device__ __forceinline__ void hidden2_acc(const unsigned char* A, int lane,
                                            f32x16 (&acc)[4][2], const f16x8 (&bf)[4][2][2]) {
    #pragma unroll
    for (int mt = 0; mt < 4; ++mt) {
        f16x8 a0 = lda(A, mt * 2, lane), a1 = lda(A, mt * 2 + 1, lane);
        acc[mt][0] = mfma32(a1, bf[2][1][0], mfma32(a0, bf[2][0][0], acc[mt][0]));
        acc[mt][1] = mfma32(a1, bf[2][1][1], mfma32(a0, bf[2][0][1], acc[mt][1]));
    }
    const unsigned char* B = A + 8192;
    #pragma unroll
    for (int mt = 0; mt < 4; ++mt) {
        f16x8 a0 = lda(B, mt * 2, lane), a1 = lda(B, mt * 2 + 1, lane);
        acc[mt][0] = mfma32(a1, bf[3][1][0], mfma32(a0, bf[3][0][0], acc[mt][0]));
        acc[mt][1] = mfma32(a1, bf[3][1][1], mfma32(a0, bf[3][0][1], acc[mt][1]));
    }
}

__device__ __forceinline__ float out_dot(const f32x16 (&acc)[4][2], const float* lwout, int hf) {
    float pt0 = 0.0f, pt1 = 0.0f;
    #pragma unroll
    for (int mt = 0; mt < 4; ++mt) {
        #pragma unroll
        for (int q = 0; q < 4; ++q) {
            f32x4 w4 = *(const f32x4*)(lwout + 32 * mt + 8 * q + 4 * hf);
            #pragma unroll
            for (int i = 0; i < 4; ++i) {
                pt0 = fmaf(tanh_fast(acc[mt][0][4 * q + i]), w4[i], pt0);
                pt1 = fmaf(tanh_fast(acc[mt][1][4 * q + i]), w4[i], pt1);
            }
        }
    }
    float s0 = pt0 + __shfl_xor(pt0, 32);
    float s1 = pt1 + __shfl_xor(pt1, 32);
    return hf ? s1 : s0;
}

__global__ __launch_bounds__(NTHREADS, 2)
void node_main(const float* __restrict__ tx, const f16* __restrict__ wsw,
               const float* __restrict__ dp_Wout, const float* __restrict__ dp_bout,
               const float* __restrict__ ic_Wout, const float* __restrict__ ic_bout,
               float* __restrict__ out)
{
    __shared__ __align__(16) unsigned char lds_w[3][16384];  // 3-slot paired ring
    __shared__ __align__(16) float lds_bias[768];
    __shared__ __align__(16) float lds_wout[2][128];
    __shared__ float lds_bout[2];

    const int tid  = threadIdx.x;
    const int lane = tid & 63;
    const int wv   = tid >> 6;
    const int l31  = lane & 31;
    const int hf   = lane >> 5;
    const int p0   = blockIdx.x * 256;

    const float* bsc = (const float*)(wsw + 2 * MLP_STRIDE);
    const float4* tx4 = (const float4*)tx;

    // ---- one-time LDS copy of bias/Wout/bout (loads retire via ds_write use,
    //      so the counted vmem window stays clean) ----
    if (tid < 768) lds_bias[tid] = bsc[tid];
    if (tid < 128) { lds_wout[0][tid] = ic_Wout[tid]; lds_wout[1][tid] = dp_Wout[tid]; }
    if (tid == 0)  { lds_bout[0] = ic_bout[0]; lds_bout[1] = dp_bout[0]; }
    __asm__ __volatile__("" ::: "memory");

    // ---- features (loads consumed into regs before prologue staging) ----
    float rA[2], xA[2], yA[2], zA[2], iA[2], aA2[2];
    #pragma unroll
    for (int nt2 = 0; nt2 < 2; ++nt2) {
        float4 tv = tx4[p0 + wv * 64 + nt2 * 32 + l31];
        float xx = tv.y, yy = tv.z, zz = tv.w;
        float rr = sqrtf(fmaf(xx, xx, fmaf(yy, yy, zz * zz)));
        float irs = 1.0f / fmaxf(rr, 1e-8f);
        rA[nt2] = rr; xA[nt2] = xx * irs; yA[nt2] = yy * irs; zA[nt2] = zz * irs;
        iA[nt2] = 1.0f / (1.0f + rr);
        aA2[nt2] = 0.5f * tv.x;
    }
    const int sown = wv * 64 + lane;
    float ao, io;
    {
        float4 tv = tx4[p0 + sown];
        float xx = tv.y, yy = tv.z, zz = tv.w;
        float rr = sqrtf(fmaf(xx, xx, fmaf(yy, yy, zz * zz)));
        io = 1.0f / (1.0f + rr);
        ao = 0.5f * tv.x;
    }

    // ---- prologue staging: chain0 G0 (ic slab0 -> slot0) + G1 (slabs1,2 -> slot1)
    {
        const f16* ic = wsw + MLP_STRIDE;
        stage_slab(ic + 0 * SLAB_F16, &lds_w[0][0], tid);
        stage_slab(ic + 1 * SLAB_F16, &lds_w[1][0], tid);
        stage_slab(ic + 2 * SLAB_F16, &lds_w[1][0] + 8192, tid);
    }

    float icv = 0.0f, dsum = 0.0f;

    #pragma unroll 1
    for (int c = 0; c < 4; ++c) {
        const f16* wb    = wsw + (c == 0 ? MLP_STRIDE : 0);
        const float* lb  = lds_bias + (c == 0 ? 384 : 0);
        const int mi     = (c == 0) ? 0 : 1;
        const float tn   = (c == 1) ? 0.22540333075851662f
                         : ((c == 2) ? 1.0f : 1.7745966692414834f);   // node+1
        const int s0     = (c == 3) ? 0 : c;   // c % 3

        // slot base for group g (g compile-time; s0 runtime scalar)
        auto SLOT = [&](int g) -> unsigned char* {
            int t = s0 + g;
            t = (t >= 6) ? t - 6 : t;
            t = (t >= 3) ? t - 3 : t;
            return &lds_w[0][0] + t * 16384;
        };

        // input-layer B frags (lanes 0..31 hold real data; upper k-half zero)
        f16x8 bfr[2];
        #pragma unroll
        for (int nt2 = 0; nt2 < 2; ++nt2) {
            f16x8 b = {};
            if (lane < 32) {
                if (c == 0) {
                    b[0] = (f16)rA[nt2]; b[1] = (f16)xA[nt2]; b[2] = (f16)yA[nt2];
                    b[3] = (f16)zA[nt2]; b[4] = (f16)iA[nt2]; b[5] = (f16)1.0f;
                } else {
                    b[0] = (f16)(aA2[nt2] * tn); b[1] = (f16)rA[nt2]; b[2] = (f16)xA[nt2];
                    b[3] = (f16)yA[nt2]; b[4] = (f16)zA[nt2]; b[5] = (f16)iA[nt2];
                    b[6] = (f16)1.0f;
                }
            }
            bfr[nt2] = b;
        }

        f32x16 acc[4][2];
        f16x8 bfrag[4][2][2];

        // S0: need G0; G1 stays in flight
        SYNC(VM4);
        stage_slab(wb + 3 * SLAB_F16, SLOT(2), tid);
        stage_slab(wb + 4 * SLAB_F16, SLOT(2) + 8192, tid);
        input_slab(SLOT(0), lane, bfr, acc);
        frag_build(acc, bfrag);

        // S1: need G1 (slabs 1,2 = l0 ks 0,1)
        SYNC(VM4);
        stage_slab(wb + 5 * SLAB_F16, SLOT(3), tid);
        stage_slab(wb + 6 * SLAB_F16, SLOT(3) + 8192, tid);
        hidden2_bias(SLOT(1), lane, hf, lb + 0 * 128, acc, bfrag);

        // S2: need G2 (slabs 3,4 = l0 ks 2,3) + frag-build
        SYNC(VM4);
        stage_slab(wb + 7 * SLAB_F16, SLOT(4), tid);
        stage_slab(wb + 8 * SLAB_F16, SLOT(4) + 8192, tid);
        hidden2_acc(SLOT(2), lane, acc, bfrag);
        frag_build(acc, bfrag);

        // S3: need G3 (slabs 5,6 = l1 ks 0,1)
        SYNC(VM4);
        stage_slab(wb + 9 * SLAB_F16, SLOT(5), tid);
        stage_slab(wb + 10 * SLAB_F16, SLOT(5) + 8192, tid);
        hidden2_bias(SLOT(3), lane, hf, lb + 1 * 128, acc, bfrag);

        // S4: need G4 (slabs 7,8 = l1 ks 2,3) + frag-build
        SYNC(VM4);
        stage_slab(wb + 11 * SLAB_F16, SLOT(6), tid);
        stage_slab(wb + 12 * SLAB_F16, SLOT(6) + 8192, tid);
        hidden2_acc(SLOT(4), lane, acc, bfrag);
        frag_build(acc, bfrag);

        // S5: need G5 (slabs 9,10 = l2 ks 0,1); stage next chain's G0
        SYNC(VM4);
        if (c < 3)
            stage_slab(wsw + 0 * SLAB_F16, SLOT(7), tid);
        hidden2_bias(SLOT(5), lane, hf, lb + 2 * 128, acc, bfrag);

        // S6: need G6 (slabs 11,12 = l2 ks 2,3); next-chain G0 (2 loads) may
        // remain in flight (in-order retirement => vmcnt(2) proves G6 done)
        if (c < 3) { SYNC(VM2); } else { SYNC(VM0); }
        if (c < 3) {
            stage_slab(wsw + 1 * SLAB_F16, SLOT(8), tid);
            stage_slab(wsw + 2 * SLAB_F16, SLOT(8) + 8192, tid);
        }
        hidden2_acc(SLOT(6), lane, acc, bfrag);

        // output layer from acc regs + LDS-resident Wout/bout
        float val = out_dot(acc, &lds_wout[mi][0], hf) + lds_bout[mi];
        if (c == 0) icv = val;
        else        dsum = fmaf((c == 2) ? (8.0f / 9.0f) : (5.0f / 9.0f), val, dsum);
    }

    out[p0 + sown] = (icv + ao * dsum) * io;
}

extern "C" void kernel_launch(void* const* d_in, const int* in_sizes, int n_in,
                              void* d_out, int out_size, void* d_ws, size_t ws_size,
                              hipStream_t stream) {
    const float* tx      = (const float*)d_in[0];
    const float* dp_Win  = (const float*)d_in[1];
    const float* dp_bin  = (const float*)d_in[2];
    const float* dp_Wh   = (const float*)d_in[3];
    const float* dp_bh   = (const float*)d_in[4];
    const float* dp_Wout = (const float*)d_in[5];
    const float* dp_bout = (const float*)d_in[6];
    const float* ic_Win  = (const float*)d_in[7];
    const float* ic_bin  = (const float*)d_in[8];
    const float* ic_Wh   = (const float*)d_in[9];
    const float* ic_bh   = (const float*)d_in[10];
    const float* ic_Wout = (const float*)d_in[11];
    const float* ic_bout = (const float*)d_in[12];
    float* out = (float*)d_out;
    f16* wsw = (f16*)d_ws;

    int n = in_sizes[0] / 4;

    prep_kernel<<<dim3((2 * MLP_STRIDE + 768 + NTHREADS - 1) / NTHREADS), dim3(NTHREADS), 0, stream>>>(
        dp_Win, dp_bin, dp_Wh, dp_bh, ic_Win, ic_bin, ic_Wh, ic_bh, wsw);

    node_main<<<dim3(n / 256), dim3(NTHREADS), 0, stream>>>(
        tx, wsw, dp_Wout, dp_bout, ic_Wout, ic_bout, out);
}

// Round 12
// 223.433 us; speedup vs baseline: 1.1124x; 1.0066x over previous
//
#include <hip/hip_runtime.h>

// NODEModel MFMA fp16, R20: restore R17 (verified best, 171.6us) + bias-copy fix.
// R18/R19 post-mortem: nt=1 3-wave occupancy arc failed twice with distinct
// modes (0.614 finite / NaN); R19's drain sync was spill-robust, so the R18
// spill diagnosis cannot cover both. Full fragment algebra (tau o C/D),
// ring schedule, and bounds re-audited clean -> abandoning the arc per
// discipline (unexplained correctness failure = model gap).
// Latent bug found in audit, fixed here: one-time bias LDS copy was
// `if (tid<768)` with only 256 threads -> copied 256/768 entries (masked
// because this problem's hidden biases are all zero). Now a strided loop.
// Everything else byte-identical to R17: in-register H via tau weight
// k-permutation, 32x32x16 MFMA, counted-vmcnt paired staging (7 sync groups,
// 3-slot x 16KB ring, VM4/VM2, never drain mid-loop), bias/Wout/bout in LDS,
// out_dot from acc regs + shfl_xor(32), tanh2_pk, launch_bounds(256,2).

#define NTHREADS 256
#define MLP_STRIDE 53248   // fp16 elems per MLP: 4096 WinA + 3*16384 Wh = 13 slabs
#define WINA_ELEMS 4096
#define SLAB_F16 4096      // 8 KB slab
#define TANH_SCALE 2.8853900817779268f   // 2*log2(e)

typedef _Float16 f16;
typedef f16 f16x8 __attribute__((ext_vector_type(8)));
typedef __fp16 fp16x2 __attribute__((ext_vector_type(2)));
typedef float f32x4 __attribute__((ext_vector_type(4)));
typedef float f32x16 __attribute__((ext_vector_type(16)));

// ---------------- prep: fp32 weights -> fp16 fragment-linear (pre-scaled) ----
// Slab layout (8KB): [mt(4)][kh(2)][lane(64)][j(8)] f16;
//   m = 32*mt + (lane&31), k_slot = base + 16*kh + 8*(lane>>5) + j.
// Hidden slabs: weight k-row = tau(k_slot) so next-layer B comes from acc regs.
__global__ __launch_bounds__(NTHREADS)
void prep_kernel(const float* __restrict__ dp_Win, const float* __restrict__ dp_bin,
                 const float* __restrict__ dp_Wh,  const float* __restrict__ dp_bh,
                 const float* __restrict__ ic_Win, const float* __restrict__ ic_bin,
                 const float* __restrict__ ic_Wh,  const float* __restrict__ ic_bh,
                 f16* __restrict__ wsw)
{
    int e = blockIdx.x * NTHREADS + threadIdx.x;
    if (e >= 2 * MLP_STRIDE + 768) return;
    if (e >= 2 * MLP_STRIDE) {          // scaled hidden biases, fp32
        int idx = e - 2 * MLP_STRIDE;   // [mlp(2)][l(3)][m(128)]
        int mlp = idx / 384, rem = idx % 384;
        const float* bh = mlp ? ic_bh : dp_bh;
        float* bsc = (float*)(wsw + 2 * MLP_STRIDE);
        bsc[idx] = bh[rem] * TANH_SCALE;
        return;
    }
    int mlp = (e >= MLP_STRIDE) ? 1 : 0;   // 0 = dp, 1 = ic
    int r = e - mlp * MLP_STRIDE;
    const float* Win = mlp ? ic_Win : dp_Win;
    const float* bin = mlp ? ic_bin : dp_bin;
    const float* Wh  = mlp ? ic_Wh  : dp_Wh;
    int din = mlp ? 5 : 6;
    float val;
    if (r < WINA_ELEMS) {
        int mt = r >> 10, kh = (r >> 9) & 1, lane = (r >> 3) & 63, j = r & 7;
        int m = mt * 32 + (lane & 31);
        int k = kh * 16 + ((lane >> 5) << 3) + j;           // feature index, natural
        val = (k < din) ? Win[k * 128 + m] : ((k == din) ? bin[m] : 0.0f);
    } else {
        int r2 = r - WINA_ELEMS;
        int l = r2 >> 14, r3 = r2 & 16383;
        int ks = r3 >> 12, mt = (r3 >> 10) & 3, kh = (r3 >> 9) & 1;
        int lane = (r3 >> 3) & 63, j = r3 & 7;
        int m = mt * 32 + (lane & 31);
        int k = ks * 32 + kh * 16 + ((lane >> 5) << 3) + j; // slot 0..127
        // tau: slot k=16t+8h'+j' holds prev-layer unit 16t+8*(j'>>2)+4h'+(j'&3)
        int kt = (k & ~15) | (((k & 7) >> 2) << 3) | (((k >> 3) & 1) << 2) | (k & 3);
        val = Wh[(l * 128 + kt) * 128 + m];
    }
    wsw[e] = (f16)(val * TANH_SCALE);
}

// ---------------- main helpers ----------------
__device__ __forceinline__ float tanh_fast(float x) {
    float e = __builtin_amdgcn_exp2f(x);
    float r = __builtin_amdgcn_rcpf(e + 1.0f);
    return fmaf(-2.0f, r, 1.0f);
}

__device__ __forceinline__ unsigned int tanh2_pk(float x0, float x1) {
    float a0 = __builtin_amdgcn_exp2f(x0) + 1.0f;
    float a1 = __builtin_amdgcn_exp2f(x1) + 1.0f;
    float n2 = -2.0f * __builtin_amdgcn_rcpf(a0 * a1);
    union { fp16x2 h; unsigned int u; } c;
    c.h = __builtin_amdgcn_cvt_pkrtz(fmaf(n2, a1, 1.0f), fmaf(n2, a0, 1.0f));
    return c.u;
}

__device__ __forceinline__ f32x16 mfma32(f16x8 a, f16x8 b, f32x16 c) {
    return __builtin_amdgcn_mfma_f32_32x32x16_f16(a, b, c, 0, 0, 0);
}

__device__ __forceinline__ void stage16(const void* g, void* l) {
    __builtin_amdgcn_global_load_lds((const __attribute__((address_space(1))) void*)g,
                                     (__attribute__((address_space(3))) void*)l, 16, 0, 0);
}

__device__ __forceinline__ void stage_slab(const f16* g, unsigned char* dst, int tid) {
    stage16((const char*)g + tid * 16, dst + tid * 16);
    stage16((const char*)g + 4096 + tid * 16, dst + 4096 + tid * 16);
}

__device__ __forceinline__ f16x8 lda(const unsigned char* A, int idx, int lane) {
    return *(const f16x8*)(A + ((idx * 64 + lane) << 4));
}

// sync: counted vmcnt + lgkmcnt(0) + barrier
#define SYNC(ENC) do { \
    __asm__ __volatile__("" ::: "memory"); \
    __builtin_amdgcn_s_waitcnt(ENC); \
    __builtin_amdgcn_s_barrier(); \
    __asm__ __volatile__("" ::: "memory"); \
} while (0)
#define VM4 0x0074   // vmcnt=4, expcnt=7, lgkmcnt=0
#define VM2 0x0072
#define VM0 0x0070

__device__ __forceinline__ void frag_build(const f32x16 (&acc)[4][2], f16x8 (&bf)[4][2][2]) {
    #pragma unroll
    for (int mt = 0; mt < 4; ++mt)
        #pragma unroll
        for (int nt = 0; nt < 2; ++nt)
            #pragma unroll
            for (int kh = 0; kh < 2; ++kh) {
                union { f16x8 f; unsigned u[4]; } w;
                #pragma unroll
                for (int q = 0; q < 4; ++q)
                    w.u[q] = tanh2_pk(acc[mt][nt][8 * kh + 2 * q],
                                      acc[mt][nt][8 * kh + 2 * q + 1]);
                bf[mt][kh][nt] = w.f;
            }
}

__device__ __forceinline__ void input_slab(const unsigned char* A, int lane,
                                           const f16x8 (&bfr)[2], f32x16 (&acc)[4][2]) {
    const f32x16 z16 = {0.f,0.f,0.f,0.f, 0.f,0.f,0.f,0.f, 0.f,0.f,0.f,0.f, 0.f,0.f,0.f,0.f};
    #pragma unroll
    for (int mt = 0; mt < 4; ++mt) {
        f16x8 a0 = lda(A, mt * 2, lane);
        acc[mt][0] = mfma32(a0, bfr[0], z16);
        acc[mt][1] = mfma32(a0, bfr[1], z16);
    }
}

// pair of slabs: first = ks2 0 (bias C-init from LDS), second = ks2 1
__device__ __forceinline__ void hidden2_bias(const unsigned char* A, int lane, int hf,
                                             const float* lb_l,
                                             f32x16 (&acc)[4][2], const f16x8 (&bf)[4][2][2]) {
    #pragma unroll
    for (int mt = 0; mt < 4; ++mt) {
        f32x16 c16;
        #pragma unroll
        for (int g2 = 0; g2 < 4; ++g2) {
            f32x4 t = *(const f32x4*)(lb_l + 32 * mt + 8 * g2 + 4 * hf);
            c16[4 * g2 + 0] = t[0]; c16[4 * g2 + 1] = t[1];
            c16[4 * g2 + 2] = t[2]; c16[4 * g2 + 3] = t[3];
        }
        f16x8 a0 = lda(A, mt * 2, lane), a1 = lda(A, mt * 2 + 1, lane);
        acc[mt][0] = mfma32(a1, bf[0][1][0], mfma32(a0, bf[0][0][0], c16));
        acc[mt][1] = mfma32(a1, bf[0][1][1], mfma32(a0, bf[0][0][1], c16));
    }
    const unsigned char* B = A + 8192;
    #pragma unroll
    for (int mt = 0; mt < 4; ++mt) {
        f16x8 a0 = lda(B, mt * 2, lane), a1 = lda(B, mt * 2 + 1, lane);
        acc[mt][0] = mfma32(a1, bf[1][1][0], mfma32(a0, bf[1][0][0], acc[mt][0]));
        acc[mt][1] = mfma32(a1, bf[1][1][1], mfma32(a0, bf[1][0][1], acc[mt][1]));
    }
}

// pair of slabs: ks2 2 then ks2 3 (accumulate)
__device__ __forceinline__ void hidden2_acc(const unsigned char* A, int lane,
                                            f32x16 (&acc)[4][2], const f16x8 (&bf)[4][2][2]) {
    #pragma unroll
    for (int mt = 0; mt < 4; ++mt) {
        f16x8 a0 = lda(A, mt * 2, lane), a1 = lda(A, mt * 2 + 1, lane);
        acc[mt][0] = mfma32(a1, bf[2][1][0], mfma32(a0, bf[2][0][0], acc[mt][0]));
        acc[mt][1] = mfma32(a1, bf[2][1][1], mfma32(a0, bf[2][0][1], acc[mt][1]));
    }
    const unsigned char* B = A + 8192;
    #pragma unroll
    for (int mt = 0; mt < 4; ++mt) {
        f16x8 a0 = lda(B, mt * 2, lane), a1 = lda(B, mt * 2 + 1, lane);
        acc[mt][0] = mfma32(a1, bf[3][1][0], mfma32(a0, bf[3][0][0], acc[mt][0]));
        acc[mt][1] = mfma32(a1, bf[3][1][1], mfma32(a0, bf[3][0][1], acc[mt][1]));
    }
}

__device__ __forceinline__ float out_dot(const f32x16 (&acc)[4][2], const float* lwout, int hf) {
    float pt0 = 0.0f, pt1 = 0.0f;
    #pragma unroll
    for (int mt = 0; mt < 4; ++mt) {
        #pragma unroll
        for (int q = 0; q < 4; ++q) {
            f32x4 w4 = *(const f32x4*)(lwout + 32 * mt + 8 * q + 4 * hf);
            #pragma unroll
            for (int i = 0; i < 4; ++i) {
                pt0 = fmaf(tanh_fast(acc[mt][0][4 * q + i]), w4[i], pt0);
                pt1 = fmaf(tanh_fast(acc[mt][1][4 * q + i]), w4[i], pt1);
            }
        }
    }
    float s0 = pt0 + __shfl_xor(pt0, 32);
    float s1 = pt1 + __shfl_xor(pt1, 32);
    return hf ? s1 : s0;
}

__global__ __launch_bounds__(NTHREADS, 2)
void node_main(const float* __restrict__ tx, const f16* __restrict__ wsw,
               const float* __restrict__ dp_Wout, const float* __restrict__ dp_bout,
               const float* __restrict__ ic_Wout, const float* __restrict__ ic_bout,
               float* __restrict__ out)
{
    __shared__ __align__(16) unsigned char lds_w[3][16384];  // 3-slot paired ring
    __shared__ __align__(16) float lds_bias[768];
    __shared__ __align__(16) float lds_wout[2][128];
    __shared__ float lds_bout[2];

    const int tid  = threadIdx.x;
    const int lane = tid & 63;
    const int wv   = tid >> 6;
    const int l31  = lane & 31;
    const int hf   = lane >> 5;
    const int p0   = blockIdx.x * 256;

    const float* bsc = (const float*)(wsw + 2 * MLP_STRIDE);
    const float4* tx4 = (const float4*)tx;

    // ---- one-time LDS copy of bias/Wout/bout (FIXED: strided loop covers all
    //      768 entries; previous `if (tid<768)` copied only 256 with 256 thr) --
    for (int i = tid; i < 768; i += NTHREADS) lds_bias[i] = bsc[i];
    if (tid < 128) { lds_wout[0][tid] = ic_Wout[tid]; lds_wout[1][tid] = dp_Wout[tid]; }
    if (tid == 0)  { lds_bout[0] = ic_bout[0]; lds_bout[1] = dp_bout[0]; }
    __asm__ __volatile__("" ::: "memory");

    // ---- features (loads consumed into regs before prologue staging) ----
    float rA[2], xA[2], yA[2], zA[2], iA[2], aA2[2];
    #pragma unroll
    for (int nt2 = 0; nt2 < 2; ++nt2) {
        float4 tv = tx4[p0 + wv * 64 + nt2 * 32 + l31];
        float xx = tv.y, yy = tv.z, zz = tv.w;
        float rr = sqrtf(fmaf(xx, xx, fmaf(yy, yy, zz * zz)));
        float irs = 1.0f / fmaxf(rr, 1e-8f);
        rA[nt2] = rr; xA[nt2] = xx * irs; yA[nt2] = yy * irs; zA[nt2] = zz * irs;
        iA[nt2] = 1.0f / (1.0f + rr);
        aA2[nt2] = 0.5f * tv.x;
    }
    const int sown = wv * 64 + lane;
    float ao, io;
    {
        float4 tv = tx4[p0 + sown];
        float xx = tv.y, yy = tv.z, zz = tv.w;
        float rr = sqrtf(fmaf(xx, xx, fmaf(yy, yy, zz * zz)));
        io = 1.0f / (1.0f + rr);
        ao = 0.5f * tv.x;
    }

    // ---- prologue staging: chain0 G0 (ic slab0 -> slot0) + G1 (slabs1,2 -> slot1)
    {
        const f16* ic = wsw + MLP_STRIDE;
        stage_slab(ic + 0 * SLAB_F16, &lds_w[0][0], tid);
        stage_slab(ic + 1 * SLAB_F16, &lds_w[1][0], tid);
        stage_slab(ic + 2 * SLAB_F16, &lds_w[1][0] + 8192, tid);
    }

    float icv = 0.0f, dsum = 0.0f;

    #pragma unroll 1
    for (int c = 0; c < 4; ++c) {
        const f16* wb    = wsw + (c == 0 ? MLP_STRIDE : 0);
        const float* lb  = lds_bias + (c == 0 ? 384 : 0);
        const int mi     = (c == 0) ? 0 : 1;
        const float tn   = (c == 1) ? 0.22540333075851662f
                         : ((c == 2) ? 1.0f : 1.7745966692414834f);   // node+1
        const int s0     = (c == 3) ? 0 : c;   // c % 3

        // slot base for group g (g compile-time; s0 runtime scalar)
        auto SLOT = [&](int g) -> unsigned char* {
            int t = s0 + g;
            t = (t >= 6) ? t - 6 : t;
            t = (t >= 3) ? t - 3 : t;
            return &lds_w[0][0] + t * 16384;
        };

        // input-layer B frags (lanes 0..31 hold real data; upper k-half zero)
        f16x8 bfr[2];
        #pragma unroll
        for (int nt2 = 0; nt2 < 2; ++nt2) {
            f16x8 b = {};
            if (lane < 32) {
                if (c == 0) {
                    b[0] = (f16)rA[nt2]; b[1] = (f16)xA[nt2]; b[2] = (f16)yA[nt2];
                    b[3] = (f16)zA[nt2]; b[4] = (f16)iA[nt2]; b[5] = (f16)1.0f;
                } else {
                    b[0] = (f16)(aA2[nt2] * tn); b[1] = (f16)rA[nt2]; b[2] = (f16)xA[nt2];
                    b[3] = (f16)yA[nt2]; b[4] = (f16)zA[nt2]; b[5] = (f16)iA[nt2];
                    b[6] = (f16)1.0f;
                }
            }
            bfr[nt2] = b;
        }

        f32x16 acc[4][2];
        f16x8 bfrag[4][2][2];

        // S0: need G0; G1 stays in flight
        SYNC(VM4);
        stage_slab(wb + 3 * SLAB_F16, SLOT(2), tid);
        stage_slab(wb + 4 * SLAB_F16, SLOT(2) + 8192, tid);
        input_slab(SLOT(0), lane, bfr, acc);
        frag_build(acc, bfrag);

        // S1: need G1 (slabs 1,2 = l0 ks 0,1)
        SYNC(VM4);
        stage_slab(wb + 5 * SLAB_F16, SLOT(3), tid);
        stage_slab(wb + 6 * SLAB_F16, SLOT(3) + 8192, tid);
        hidden2_bias(SLOT(1), lane, hf, lb + 0 * 128, acc, bfrag);

        // S2: need G2 (slabs 3,4 = l0 ks 2,3) + frag-build
        SYNC(VM4);
        stage_slab(wb + 7 * SLAB_F16, SLOT(4), tid);
        stage_slab(wb + 8 * SLAB_F16, SLOT(4) + 8192, tid);
        hidden2_acc(SLOT(2), lane, acc, bfrag);
        frag_build(acc, bfrag);

        // S3: need G3 (slabs 5,6 = l1 ks 0,1)
        SYNC(VM4);
        stage_slab(wb + 9 * SLAB_F16, SLOT(5), tid);
        stage_slab(wb + 10 * SLAB_F16, SLOT(5) + 8192, tid);
        hidden2_bias(SLOT(3), lane, hf, lb + 1 * 128, acc, bfrag);

        // S4: need G4 (slabs 7,8 = l1 ks 2,3) + frag-build
        SYNC(VM4);
        stage_slab(wb + 11 * SLAB_F16, SLOT(6), tid);
        stage_slab(wb + 12 * SLAB_F16, SLOT(6) + 8192, tid);
        hidden2_acc(SLOT(4), lane, acc, bfrag);
        frag_build(acc, bfrag);

        // S5: need G5 (slabs 9,10 = l2 ks 0,1); stage next chain's G0
        SYNC(VM4);
        if (c < 3)
            stage_slab(wsw + 0 * SLAB_F16, SLOT(7), tid);
        hidden2_bias(SLOT(5), lane, hf, lb + 2 * 128, acc, bfrag);

        // S6: need G6 (slabs 11,12 = l2 ks 2,3); next-chain G0 (2 loads) may
        // remain in flight (in-order retirement => vmcnt(2) proves G6 done)
        if (c < 3) { SYNC(VM2); } else { SYNC(VM0); }
        if (c < 3) {
            stage_slab(wsw + 1 * SLAB_F16, SLOT(8), tid);
            stage_slab(wsw + 2 * SLAB_F16, SLOT(8) + 8192, tid);
        }
        hidden2_acc(SLOT(6), lane, acc, bfrag);

        // output layer from acc regs + LDS-resident Wout/bout
        float val = out_dot(acc, &lds_wout[mi][0], hf) + lds_bout[mi];
        if (c == 0) icv = val;
        else        dsum = fmaf((c == 2) ? (8.0f / 9.0f) : (5.0f / 9.0f), val, dsum);
    }

    out[p0 + sown] = (icv + ao * dsum) * io;
}

extern "C" void kernel_launch(void* const* d_in, const int* in_sizes, int n_in,
                              void* d_out, int out_size, void* d_ws, size_t ws_size,
                              hipStream_t stream) {
    const float* tx      = (const float*)d_in[0];
    const float* dp_Win  = (const float*)d_in[1];
    const float* dp_bin  = (const float*)d_in[2];
    const float* dp_Wh   = (const float*)d_in[3];
    const float* dp_bh   = (const float*)d_in[4];
    const float* dp_Wout = (const float*)d_in[5];
    const float* dp_bout = (const float*)d_in[6];
    const float* ic_Win  = (const float*)d_in[7];
    const float* ic_bin  = (const float*)d_in[8];
    const float* ic_Wh   = (const float*)d_in[9];
    const float* ic_bh   = (const float*)d_in[10];
    const float* ic_Wout = (const float*)d_in[11];
    const float* ic_bout = (const float*)d_in[12];
    float* out = (float*)d_out;
    f16* wsw = (f16*)d_ws;

    int n = in_sizes[0] / 4;

    prep_kernel<<<dim3((2 * MLP_STRIDE + 768 + NTHREADS - 1) / NTHREADS), dim3(NTHREADS), 0, stream>>>(
        dp_Win, dp_bin, dp_Wh, dp_bh, ic_Win, ic_bin, ic_Wh, ic_bh, wsw);

    node_main<<<dim3(n / 256), dim3(NTHREADS), 0, stream>>>(
        tx, wsw, dp_Wout, dp_bout, ic_Wout, ic_bout, out);
}